// Round 1
// 1377.535 us; speedup vs baseline: 1.0344x; 1.0344x over previous
//
#include <hip/hip_runtime.h>

// Problem constants: N=Na=10000, d_in=256, d_out=64, n_rel=3
#define NN    10000
#define NA    10000
#define DIN   256
#define DOUT  64
#define INV_T (1.0f / 0.07f)
#define CAP   1024   // max adjacency-true entries per row; Binomial(10000,0.01) max ~150

typedef unsigned int uv4 __attribute__((ext_vector_type(4)));  // nt-loadable uint4

// adjs layout: int32-per-bool, A/B-verified on this harness:
//   R1 assumed byte layout -> wrong-column outputs (absmax 0.20);
//   R2 runtime-detect      -> passed (absmax 2.4e-4).
// Hardcoded here to remove the serialized detect launch.
//
// R3 experiment: Phase A MLP restructure. Batch all 10 NT uint4 loads into
// registers BEFORE any test (10 outstanding/wave vs ~1-2 when interleaved
// with test+atomic), reduce to a 40-bit hit mask (values never needed),
// one batched LDS atomicAdd per thread instead of one per hit.
// Discriminates: H1 kernel-latency-bound (dur_us -> ~900) vs
//                H2 harness-fill-bound (dur_us unchanged +-2%).

// ---- Fused kernel: proj + sparse masked-softmax attention. One block/row. ----
__global__ __launch_bounds__(256) void attn_kernel(
    const float* __restrict__ x,        // [NN, DOUT]
    const float* __restrict__ weight,   // [n_rel]
    const unsigned int* __restrict__ adjs, // [n_rel, NA, NN] int32 bools
    const int*   __restrict__ idxp,     // [1]
    const float* __restrict__ anchor,   // [NA, DIN]
    const float* __restrict__ wt,       // [DIN, DOUT]
    float* __restrict__ out)            // [NA, DOUT]
{
    __shared__ float arow[DIN];   // anchor row
    __shared__ float pr[DOUT];    // projected row
    __shared__ int   jl[CAP];
    __shared__ float ps[CAP];
    __shared__ float red[256];
    __shared__ float wred[8];     // per-wave softmax partials (max: 0..3, sum: 4..7)
    __shared__ int   cnt;

    const int t    = threadIdx.x;
    const int row  = blockIdx.x;
    const int w    = t >> 6;      // wave id
    const int lane = t & 63;

    // stage anchor row (256 floats = 64 float4) + zero the compaction counter
    if (t < 64) ((float4*)arow)[t] =
        ((const float4*)(anchor + (size_t)row * DIN))[t];
    if (t == 0) cnt = 0;
    __syncthreads();

    const int idx = idxp[0];

    // ---- Phase A: NT scan of adj row (2500 uint4 = 10000 int32), compact ----
    {
        const uv4* ar = (const uv4*)(adjs + ((size_t)idx * NA + row) * NN);
        // 1) issue ALL loads first -> 10 outstanding 16B NT loads per thread
        uv4 v[10];
#pragma unroll
        for (int it = 0; it < 10; ++it) {
            const int cch = t + 256 * it;
            uv4 vv = {0u, 0u, 0u, 0u};
            if (cch < NN / 4) vv = __builtin_nontemporal_load(ar + cch);
            v[it] = vv;
        }
        // 2) reduce to 40-bit hit mask (bit b = word b nonzero); values dead after this
        unsigned long long hm = 0ull;
#pragma unroll
        for (int it = 0; it < 10; ++it) {
            unsigned int nz = (v[it].x ? 1u : 0u) | (v[it].y ? 2u : 0u) |
                              (v[it].z ? 4u : 0u) | (v[it].w ? 8u : 0u);
            hm |= (unsigned long long)nz << (it * 4);
        }
        // 3) one batched atomic per thread, then scatter indices
        const int mycnt = __popcll(hm);
        int base = 0;
        if (mycnt) base = atomicAdd(&cnt, mycnt);
        while (hm) {
            const int b = __ffsll((long long)hm) - 1;   // word index 0..39
            hm &= hm - 1;
            const int it = b >> 2, ww = b & 3;
            if (base < CAP) jl[base] = (t + 256 * it) * 4 + ww;
            ++base;
        }
    }

    // ---- Phase P (same barrier interval): proj[row] = anchor[row] @ wt ----
    {
        const int seg = t >> 6, c = t & 63;
        float acc = 0.f;
        const int k0 = seg * 64;
#pragma unroll 8
        for (int k = k0; k < k0 + 64; ++k)
            acc = fmaf(arow[k], wt[k * DOUT + c], acc);  // wt coalesced across c
        red[t] = acc;
    }
    __syncthreads();   // finalizes cnt, jl, and proj partials

    if (t < DOUT) pr[t] = red[t] + red[64 + t] + red[128 + t] + red[192 + t];
    int nc = cnt; if (nc > CAP) nc = CAP;
    __syncthreads();

    if (nc == 0) {  // cannot occur at 1% density with this seed; stay defined
        if (t < DOUT) out[(size_t)row * DOUT + t] = 0.f;
        return;
    }

    // ---- Phase B: scores; 16 lanes cooperate per score (float4 per lane) ----
    {
        const int g = t >> 4, l = t & 15;
        const float4 pv = ((const float4*)pr)[l];
        for (int s = g; s < nc; s += 16) {
            const int j = jl[s];
            float4 xv = ((const float4*)(x + (size_t)j * DOUT))[l];
            float d = xv.x * pv.x + xv.y * pv.y + xv.z * pv.z + xv.w * pv.w;
            d += __shfl_xor(d, 1);
            d += __shfl_xor(d, 2);
            d += __shfl_xor(d, 4);
            d += __shfl_xor(d, 8);
            if (l == 0) ps[s] = d * INV_T;
        }
    }
    __syncthreads();

    // ---- Phase C: softmax (wave-shuffle reductions, 2 barriers total) ----
    float lm = -3.4e38f;
    for (int s = t; s < nc; s += 256) lm = fmaxf(lm, ps[s]);
#pragma unroll
    for (int o = 32; o > 0; o >>= 1) lm = fmaxf(lm, __shfl_xor(lm, o));
    if (lane == 0) wred[w] = lm;
    __syncthreads();
    const float m = fmaxf(fmaxf(wred[0], wred[1]), fmaxf(wred[2], wred[3]));

    float lsum = 0.f;
    for (int s = t; s < nc; s += 256) {
        float p = __expf(ps[s] - m);
        ps[s] = p;
        lsum += p;
    }
#pragma unroll
    for (int o = 32; o > 0; o >>= 1) lsum += __shfl_xor(lsum, o);
    if (lane == 0) wred[4 + w] = lsum;
    __syncthreads();   // also finalizes ps[] for Phase D
    const float scale = weight[idx] /
        (wred[4] + wred[5] + wred[6] + wred[7]);

    // ---- Phase D: out[row,:] = scale * sum_s ps[s] * x[jl[s],:] ----
    {
        const int c = t & 63, seg = t >> 6;
        float acc = 0.f;
        for (int s = seg; s < nc; s += 4)
            acc = fmaf(ps[s], x[(size_t)jl[s] * DOUT + c], acc);
        red[t] = acc;
        __syncthreads();
        if (t < DOUT) {
            float o = (red[t] + red[64 + t] + red[128 + t] + red[192 + t]) * scale;
            __builtin_nontemporal_store(o, out + (size_t)row * DOUT + t);
        }
    }
}

extern "C" void kernel_launch(void* const* d_in, const int* in_sizes, int n_in,
                              void* d_out, int out_size, void* d_ws, size_t ws_size,
                              hipStream_t stream) {
    const float*        x      = (const float*)d_in[0];
    const float*        weight = (const float*)d_in[1];
    const unsigned int* adjs   = (const unsigned int*)d_in[2];
    const int*          idxp   = (const int*)d_in[3];
    const float*        anchor = (const float*)d_in[4];
    const float*        wt     = (const float*)d_in[5];
    float*              out    = (float*)d_out;

    attn_kernel<<<NA, 256, 0, stream>>>(x, weight, adjs, idxp, anchor, wt, out);
}